// Round 5
// baseline (190.340 us; speedup 1.0000x reference)
//
#include <hip/hip_runtime.h>

// ContractExpand via bf16 MFMA, split-pipeline:
//   K1 seg_and_w: per (b, 100-row L-chunk) block, read x once; write bf16
//     A-matrices for all scales (x itself = r1) into d_ws, K padded to 320;
//     8 extra blocks convert W fp32->bf16 [5][320][320].
//   K2 ce_mfma5: per 32-row tile: MFMA with A,B straight from global bf16
//     (L2/L3-hot); bias+relu+/r -> LDS fp32 [32][304]; coalesced
//     non-temporal float4 stores incl. r-repeats.
// Fallback to the round-4 fused kernel if ws_size is too small.

typedef short bf16x8 __attribute__((ext_vector_type(8)));
typedef float f32x4  __attribute__((ext_vector_type(4)));

namespace {
constexpr int D    = 300;
constexpr int LSEQ = 800;
constexpr int KP   = 320;
constexpr int NP   = 320;
constexpr int CSTR = 304;
constexpr int SMEM_BYTES = 32 * CSTR * 4;            // 38912
constexpr size_t WB_SHORTS = (size_t)5 * NP * KP;    // 512000
constexpr size_t A1_OFF  = WB_SHORTS;                           // 51200 rows
constexpr size_t A2_OFF  = A1_OFF  + (size_t)51200 * KP;        // 25600 rows
constexpr size_t A4_OFF  = A2_OFF  + (size_t)25600 * KP;        // 12800 rows
constexpr size_t A10_OFF = A4_OFF  + (size_t)12800 * KP;        //  5120 rows
constexpr size_t A25_OFF = A10_OFF + (size_t)5120  * KP;        //  2048 rows
constexpr size_t WS_NEEDED = (A25_OFF + (size_t)2048 * KP) * 2; // ~63 MB
}

__device__ __forceinline__ unsigned short f2bf(float f) {
  unsigned u = __float_as_uint(f);
  u += 0x7fffu + ((u >> 16) & 1u);   // RNE
  return (unsigned short)(u >> 16);
}

// ===================== K1: segment sums + W convert =====================

template<int R>
__device__ __forceinline__ void seg_scale(const float* __restrict__ xb,
    short* __restrict__ Ab, int b, int chunk, int tid) {
  constexpr int GC = 100 / R;          // groups in this 100-row chunk
  constexpr int G  = LSEQ / R;         // groups per batch row
  for (int i = tid; i < GC * 40; i += 256) {
    const int row = i / 40;
    const int k0  = (i - row * 40) * 8;
    float s[8];
    #pragma unroll
    for (int j = 0; j < 8; ++j) s[j] = 0.f;
    const float* xp = xb + ((size_t)(chunk * 100 + row * R)) * D + k0;
    if (k0 < 296) {
      #pragma unroll
      for (int q = 0; q < R; ++q) {
        const float4 v0 = *(const float4*)(xp + (size_t)q * D);
        const float4 v1 = *(const float4*)(xp + (size_t)q * D + 4);
        s[0] += v0.x; s[1] += v0.y; s[2] += v0.z; s[3] += v0.w;
        s[4] += v1.x; s[5] += v1.y; s[6] += v1.z; s[7] += v1.w;
      }
    } else if (k0 == 296) {
      #pragma unroll
      for (int q = 0; q < R; ++q) {
        const float4 v0 = *(const float4*)(xp + (size_t)q * D);
        s[0] += v0.x; s[1] += v0.y; s[2] += v0.z; s[3] += v0.w;
      }
    }
    bf16x8 p;
    #pragma unroll
    for (int j = 0; j < 8; ++j) p[j] = (short)f2bf(s[j]);
    *(bf16x8*)(Ab + ((size_t)(b * G + chunk * GC + row)) * KP + k0) = p;
  }
}

__global__ __launch_bounds__(256)
void seg_and_w(const float* __restrict__ x, const float* __restrict__ W,
               short* __restrict__ ws) {
  const int bid = blockIdx.x, tid = threadIdx.x;
  if (bid < 512) {
    const int b = bid >> 3, chunk = bid & 7;
    const float* xb = x + (size_t)b * LSEQ * D;
    seg_scale<1 >(xb, ws + A1_OFF,  b, chunk, tid);
    seg_scale<2 >(xb, ws + A2_OFF,  b, chunk, tid);
    seg_scale<4 >(xb, ws + A4_OFF,  b, chunk, tid);
    seg_scale<10>(xb, ws + A10_OFF, b, chunk, tid);
    seg_scale<25>(xb, ws + A25_OFF, b, chunk, tid);
  } else {
    // W -> bf16 padded [5][320][320]; 8 blocks x 256 threads
    const int t0 = (bid - 512) * 256 + tid;
    for (int item = t0; item < 5 * NP * KP / 8; item += 2048) {
      const int off = item * 8;
      const int n   = off / (NP * KP);
      const int rem = off - n * (NP * KP);
      const int c = rem / KP, k0 = rem - c * KP;
      float s[8];
      #pragma unroll
      for (int j = 0; j < 8; ++j) s[j] = 0.f;
      if (c < D) {
        const float* wp = W + (size_t)n * D * D + (size_t)c * D + k0;
        if (k0 < 296) {
          const float4 v0 = *(const float4*)(wp);
          const float4 v1 = *(const float4*)(wp + 4);
          s[0] = v0.x; s[1] = v0.y; s[2] = v0.z; s[3] = v0.w;
          s[4] = v1.x; s[5] = v1.y; s[6] = v1.z; s[7] = v1.w;
        } else if (k0 == 296) {
          const float4 v0 = *(const float4*)(wp);
          s[0] = v0.x; s[1] = v0.y; s[2] = v0.z; s[3] = v0.w;
        }
      }
      bf16x8 p;
      #pragma unroll
      for (int j = 0; j < 8; ++j) p[j] = (short)f2bf(s[j]);
      *(bf16x8*)(ws + (size_t)off) = p;
    }
  }
}

// ===================== K2: MFMA + epilogue + stores =====================

template<int N, int R, int G>
__device__ __forceinline__ void ce_body5(const int tile, char* __restrict__ smem,
    const short* __restrict__ ws, const float* __restrict__ bias,
    float* __restrict__ out) {
  const short* __restrict__ Ab = ws +
      (N == 0 ? A1_OFF : N == 1 ? A2_OFF : N == 2 ? A4_OFF : N == 3 ? A10_OFF : A25_OFF);
  const short* __restrict__ Wn = ws + (size_t)N * NP * KP;

  const int tid  = threadIdx.x;
  const int m0   = tile * 32;
  const int wv   = tid >> 6;
  const int lane = tid & 63;
  const int cr   = lane & 15;    // A row / B col / C col
  const int kh   = lane >> 4;    // k-half; C row = kh*4 + reg

  const short* __restrict__ ar0 = Ab + (size_t)(m0 + cr) * KP + kh * 8;
  const short* __restrict__ ar1 = ar0 + (size_t)16 * KP;

  f32x4 acc[2][5];
  #pragma unroll
  for (int mt = 0; mt < 2; ++mt)
    #pragma unroll
    for (int t = 0; t < 5; ++t) acc[mt][t] = (f32x4){0.f, 0.f, 0.f, 0.f};

  #pragma unroll
  for (int ks = 0; ks < 10; ++ks) {
    const bf16x8 a0 = *(const bf16x8*)(ar0 + ks * 32);
    const bf16x8 a1 = *(const bf16x8*)(ar1 + ks * 32);
    #pragma unroll
    for (int t = 0; t < 5; ++t) {
      const int col = (wv * 5 + t) * 16 + cr;
      const bf16x8 bf = *(const bf16x8*)(Wn + (size_t)col * KP + ks * 32 + kh * 8);
      acc[0][t] = __builtin_amdgcn_mfma_f32_16x16x32_bf16(a0, bf, acc[0][t], 0, 0, 0);
      acc[1][t] = __builtin_amdgcn_mfma_f32_16x16x32_bf16(a1, bf, acc[1][t], 0, 0, 0);
    }
  }

  // bias + relu + /R -> fp32 LDS tile [32][CSTR]
  float* __restrict__ cout = (float*)smem;
  const float inv_r = 1.0f / (float)R;
  #pragma unroll
  for (int t = 0; t < 5; ++t) {
    const int col = (wv * 5 + t) * 16 + cr;
    if (col < D) {
      const float bv = bias[N * D + col];
      #pragma unroll
      for (int mt = 0; mt < 2; ++mt)
        #pragma unroll
        for (int j = 0; j < 4; ++j) {
          const int row = mt * 16 + kh * 4 + j;
          cout[row * CSTR + col] = fmaxf(acc[mt][t][j] + bv, 0.f) * inv_r;
        }
    }
  }
  __syncthreads();

  // coalesced non-temporal float4 stores, repeats included
  constexpr int TOTAL = 32 * R * 75;
  for (int i = tid; i < TOTAL; i += 256) {
    const int rowrep = i / 75;
    const int chunk  = i - rowrep * 75;
    const int ml     = rowrep / R;
    const int q      = rowrep - ml * R;
    const int m      = m0 + ml;
    const int bb     = m / G;
    const int grp    = m - bb * G;
    const f32x4 v = *(const f32x4*)(cout + ml * CSTR + chunk * 4);
    float* __restrict__ op =
        out + ((size_t)((N * 64 + bb) * LSEQ) + grp * R + q) * D + chunk * 4;
    __builtin_nontemporal_store(v, (f32x4*)op);
  }
}

__global__ __launch_bounds__(256, 4)
void ce_mfma5(const short* __restrict__ ws, const float* __restrict__ bias,
              float* __restrict__ out) {
  __shared__ __align__(16) char smem[SMEM_BYTES];
  const int bid = blockIdx.x;
  if (bid < 64)        ce_body5<4, 25, 32 >(bid,        smem, ws, bias, out);
  else if (bid < 224)  ce_body5<3, 10, 80 >(bid - 64,   smem, ws, bias, out);
  else if (bid < 624)  ce_body5<2, 4, 200 >(bid - 224,  smem, ws, bias, out);
  else if (bid < 1424) ce_body5<1, 2, 400 >(bid - 624,  smem, ws, bias, out);
  else                 ce_body5<0, 1, 800 >(bid - 1424, smem, ws, bias, out);
}

// ===================== Fallback (round-4 fused, needs only Wb) =====================

__global__ void convert_w(const float* __restrict__ W, short* __restrict__ Wb) {
  int idx = blockIdx.x * 256 + threadIdx.x;
  if (idx >= 5 * NP * KP) return;
  int n   = idx / (NP * KP);
  int rem = idx - n * NP * KP;
  int c = rem / KP, k = rem - c * KP;
  float v = (c < D && k < D) ? W[(size_t)n * D * D + (size_t)c * D + k] : 0.f;
  Wb[idx] = (short)f2bf(v);
}

template<int N, int R, int G>
__device__ __forceinline__ void ce_body4(const int tile, char* __restrict__ smem,
    const float* __restrict__ x, const short* __restrict__ Wb,
    const float* __restrict__ bias, float* __restrict__ out) {
  const int tid = threadIdx.x;
  const int m0  = tile * 32;
  #pragma unroll
  for (int it = 0; it < 5; ++it) {
    const int cidx = tid + it * 256;
    const int row  = cidx / 40;
    const int k0   = (cidx - row * 40) * 8;
    float s[8];
    #pragma unroll
    for (int j = 0; j < 8; ++j) s[j] = 0.f;
    if (k0 < D) {
      const int m   = m0 + row;
      const int bb  = m / G;
      const int grp = m - bb * G;
      const float* xp = x + ((size_t)(bb * LSEQ + grp * R)) * D + k0;
      if (k0 <= D - 8) {
        #pragma unroll
        for (int q = 0; q < R; ++q) {
          const float4 v0 = *(const float4*)(xp + (size_t)q * D);
          const float4 v1 = *(const float4*)(xp + (size_t)q * D + 4);
          s[0] += v0.x; s[1] += v0.y; s[2] += v0.z; s[3] += v0.w;
          s[4] += v1.x; s[5] += v1.y; s[6] += v1.z; s[7] += v1.w;
        }
      } else {
        #pragma unroll
        for (int q = 0; q < R; ++q) {
          const float4 v0 = *(const float4*)(xp + (size_t)q * D);
          s[0] += v0.x; s[1] += v0.y; s[2] += v0.z; s[3] += v0.w;
        }
      }
    }
    bf16x8 p;
    #pragma unroll
    for (int j = 0; j < 8; ++j) p[j] = (short)f2bf(s[j]);
    const int boff = (row * 640 + k0 * 2) ^ ((row & 7) << 4);
    *(bf16x8*)(smem + boff) = p;
  }
  __syncthreads();

  const int wv   = tid >> 6;
  const int lane = tid & 63;
  const int cr   = lane & 15;
  const int kh   = lane >> 4;

  f32x4 acc[2][5];
  #pragma unroll
  for (int mt = 0; mt < 2; ++mt)
    #pragma unroll
    for (int t = 0; t < 5; ++t) acc[mt][t] = (f32x4){0.f, 0.f, 0.f, 0.f};

  const short* __restrict__ Wn = Wb + (size_t)N * NP * KP;
  const int swz0 = (cr & 7) << 4;
  #pragma unroll
  for (int ks = 0; ks < 10; ++ks) {
    const int b0 = (cr * 640        + ks * 64 + kh * 16) ^ swz0;
    const int b1 = ((16 + cr) * 640 + ks * 64 + kh * 16) ^ swz0;
    const bf16x8 a0 = *(const bf16x8*)(smem + b0);
    const bf16x8 a1 = *(const bf16x8*)(smem + b1);
    #pragma unroll
    for (int t = 0; t < 5; ++t) {
      const int col = (wv * 5 + t) * 16 + cr;
      const bf16x8 bf = *(const bf16x8*)(Wn + (size_t)col * KP + ks * 32 + kh * 8);
      acc[0][t] = __builtin_amdgcn_mfma_f32_16x16x32_bf16(a0, bf, acc[0][t], 0, 0, 0);
      acc[1][t] = __builtin_amdgcn_mfma_f32_16x16x32_bf16(a1, bf, acc[1][t], 0, 0, 0);
    }
  }
  __syncthreads();

  float* __restrict__ cout = (float*)smem;
  const float inv_r = 1.0f / (float)R;
  #pragma unroll
  for (int t = 0; t < 5; ++t) {
    const int col = (wv * 5 + t) * 16 + cr;
    if (col < D) {
      const float bv = bias[N * D + col];
      #pragma unroll
      for (int mt = 0; mt < 2; ++mt)
        #pragma unroll
        for (int j = 0; j < 4; ++j) {
          const int row = mt * 16 + kh * 4 + j;
          cout[row * CSTR + col] = fmaxf(acc[mt][t][j] + bv, 0.f) * inv_r;
        }
    }
  }
  __syncthreads();

  constexpr int TOTAL = 32 * R * 75;
  for (int i = tid; i < TOTAL; i += 256) {
    const int rowrep = i / 75;
    const int chunk  = i - rowrep * 75;
    const int ml     = rowrep / R;
    const int q      = rowrep - ml * R;
    const int m      = m0 + ml;
    const int bb     = m / G;
    const int grp    = m - bb * G;
    const f32x4 v = *(const f32x4*)(cout + ml * CSTR + chunk * 4);
    float* __restrict__ op =
        out + ((size_t)((N * 64 + bb) * LSEQ) + grp * R + q) * D + chunk * 4;
    *(f32x4*)op = v;
  }
}

__global__ __launch_bounds__(256, 4)
void ce_mfma4(const float* __restrict__ x, const short* __restrict__ Wb,
              const float* __restrict__ bias, float* __restrict__ out) {
  __shared__ __align__(16) char smem[SMEM_BYTES];
  const int bid = blockIdx.x;
  if (bid < 64)        ce_body4<4, 25, 32 >(bid,        smem, x, Wb, bias, out);
  else if (bid < 224)  ce_body4<3, 10, 80 >(bid - 64,   smem, x, Wb, bias, out);
  else if (bid < 624)  ce_body4<2, 4, 200 >(bid - 224,  smem, x, Wb, bias, out);
  else if (bid < 1424) ce_body4<1, 2, 400 >(bid - 624,  smem, x, Wb, bias, out);
  else                 ce_body4<0, 1, 800 >(bid - 1424, smem, x, Wb, bias, out);
}

extern "C" void kernel_launch(void* const* d_in, const int* in_sizes, int n_in,
                              void* d_out, int out_size, void* d_ws, size_t ws_size,
                              hipStream_t stream) {
  const float* x    = (const float*)d_in[0];  // [64, 800, 300]
  const float* W    = (const float*)d_in[1];  // [5, 300, 300]
  const float* bias = (const float*)d_in[2];  // [5, 300]
  float* out        = (float*)d_out;          // [5, 64, 800, 300]
  short* ws         = (short*)d_ws;

  if (ws_size >= WS_NEEDED) {
    seg_and_w<<<520, 256, 0, stream>>>(x, W, ws);
    ce_mfma5<<<3024, 256, 0, stream>>>(ws, bias, out);
  } else {
    convert_w<<<(5 * NP * KP + 255) / 256, 256, 0, stream>>>(W, ws);
    ce_mfma4<<<3024, 256, 0, stream>>>(x, ws, bias, out);
  }
}

// Round 6
// 173.362 us; speedup vs baseline: 1.0979x; 1.0979x over previous
//
#include <hip/hip_runtime.h>

// ContractExpand via bf16 MFMA, fused, super-chunk-interleaved block order:
//   out[n,b,l,:] = relu(seg_r(x)[b, l/r, :] @ W[n]^T + bias[n]) / r,  r={1,2,4,10,25}
// Grid: 16 super-chunks x 189 blocks; each super-chunk covers the SAME 4-batch-row
// x-window for all 5 scales (heavy-r first) -> x is L2/L3-hot, read ~once from HBM.
// Per block (32 group-rows of one scale):
//   R>1 : p1 seg-sum fp32 -> bf16 XOR-swizzled LDS; p2 MFMA (A from LDS, B from
//         global bf16 W); p3 bias+relu+/r -> fp32 LDS; p4 coalesced float4 stores.
//   R==1: A-frags straight from global x with in-reg cvt (no p1, one barrier);
//         k>=300 garbage killed by Wb zero-padding; last-row frags bounds-checked.

typedef short bf16x8 __attribute__((ext_vector_type(8)));
typedef float f32x4  __attribute__((ext_vector_type(4)));

namespace {
constexpr int D    = 300;
constexpr int LSEQ = 800;
constexpr int KP   = 320;   // padded K (10 steps of 32)
constexpr int NP   = 320;   // padded N rows of Wb
constexpr int CSTR = 304;   // cout row stride (floats)
constexpr int SMEM_BYTES = 32 * CSTR * 4;   // 38912 B >= 32*320*2
constexpr size_t TOTX = (size_t)64 * LSEQ * D;
}

__device__ __forceinline__ unsigned short f2bf(float f) {
  unsigned u = __float_as_uint(f);
  u += 0x7fffu + ((u >> 16) & 1u);   // RNE
  return (unsigned short)(u >> 16);
}

__global__ void convert_w(const float* __restrict__ W, short* __restrict__ Wb) {
  int idx = blockIdx.x * 256 + threadIdx.x;
  if (idx >= 5 * NP * KP) return;
  int n   = idx / (NP * KP);
  int rem = idx - n * (NP * KP);
  int c = rem / KP, k = rem - c * KP;
  float v = (c < D && k < D) ? W[(size_t)n * D * D + (size_t)c * D + k] : 0.f;
  Wb[idx] = (short)f2bf(v);
}

__device__ __forceinline__ bf16x8 load_cvt_guard(const float* __restrict__ x, size_t fl) {
  float4 v0 = {0.f, 0.f, 0.f, 0.f}, v1 = {0.f, 0.f, 0.f, 0.f};
  if (fl + 4 <= TOTX) v0 = *(const float4*)(x + fl);
  if (fl + 8 <= TOTX) v1 = *(const float4*)(x + fl + 4);
  bf16x8 a;
  a[0] = (short)f2bf(v0.x); a[1] = (short)f2bf(v0.y);
  a[2] = (short)f2bf(v0.z); a[3] = (short)f2bf(v0.w);
  a[4] = (short)f2bf(v1.x); a[5] = (short)f2bf(v1.y);
  a[6] = (short)f2bf(v1.z); a[7] = (short)f2bf(v1.w);
  return a;
}

template<int N, int R, int G>
__device__ __forceinline__ void ce_body(const int tile, char* __restrict__ smem,
    const float* __restrict__ x, const short* __restrict__ Wb,
    const float* __restrict__ bias, float* __restrict__ out) {
  const int tid = threadIdx.x;
  const int m0  = tile * 32;                 // first group-row; M_total = 64*G

  if (R > 1) {
    // ---- phase 1: seg-sums fp32 -> bf16 swizzled LDS [32 rows][320 cols] ----
    #pragma unroll
    for (int it = 0; it < 5; ++it) {
      const int cidx = tid + it * 256;       // 0..1279 = 32 rows x 40 chunks
      const int row  = cidx / 40;
      const int k0   = (cidx - row * 40) * 8;
      float s[8];
      #pragma unroll
      for (int j = 0; j < 8; ++j) s[j] = 0.f;
      if (k0 < D) {
        const int m   = m0 + row;
        const int bb  = m / G;
        const int grp = m - bb * G;
        const float* xp = x + ((size_t)(bb * LSEQ + grp * R)) * D + k0;
        if (k0 <= D - 8) {
          #pragma unroll
          for (int q = 0; q < R; ++q) {
            const float4 v0 = *(const float4*)(xp + (size_t)q * D);
            const float4 v1 = *(const float4*)(xp + (size_t)q * D + 4);
            s[0] += v0.x; s[1] += v0.y; s[2] += v0.z; s[3] += v0.w;
            s[4] += v1.x; s[5] += v1.y; s[6] += v1.z; s[7] += v1.w;
          }
        } else {                             // k0 == 296
          #pragma unroll
          for (int q = 0; q < R; ++q) {
            const float4 v0 = *(const float4*)(xp + (size_t)q * D);
            s[0] += v0.x; s[1] += v0.y; s[2] += v0.z; s[3] += v0.w;
          }
        }
      }
      bf16x8 p;
      #pragma unroll
      for (int j = 0; j < 8; ++j) p[j] = (short)f2bf(s[j]);
      const int boff = (row * 640 + k0 * 2) ^ ((row & 7) << 4);
      *(bf16x8*)(smem + boff) = p;
    }
    __syncthreads();
  }

  // ---- phase 2: MFMA.  B from global bf16 W (L2-hot) ----
  const int wv   = tid >> 6;
  const int lane = tid & 63;
  const int cr   = lane & 15;    // A row / B col / C col
  const int kh   = lane >> 4;    // k-half; C row = kh*4 + reg

  f32x4 acc[2][5];
  #pragma unroll
  for (int mt = 0; mt < 2; ++mt)
    #pragma unroll
    for (int t = 0; t < 5; ++t) acc[mt][t] = (f32x4){0.f, 0.f, 0.f, 0.f};

  const short* __restrict__ Wn = Wb + (size_t)N * NP * KP;
  const short* __restrict__ wp[5];
  #pragma unroll
  for (int t = 0; t < 5; ++t)
    wp[t] = Wn + (size_t)((wv * 5 + t) * 16 + cr) * KP + kh * 8;

  if (R == 1) {
    const size_t row0 = (size_t)(m0 + cr) * D + kh * 8;
    const size_t row1 = (size_t)(m0 + 16 + cr) * D + kh * 8;
    #pragma unroll
    for (int ks = 0; ks < 10; ++ks) {
      const bf16x8 a0 = load_cvt_guard(x, row0 + ks * 32);
      const bf16x8 a1 = load_cvt_guard(x, row1 + ks * 32);
      #pragma unroll
      for (int t = 0; t < 5; ++t) {
        const bf16x8 bf = *(const bf16x8*)(wp[t] + ks * 32);
        acc[0][t] = __builtin_amdgcn_mfma_f32_16x16x32_bf16(a0, bf, acc[0][t], 0, 0, 0);
        acc[1][t] = __builtin_amdgcn_mfma_f32_16x16x32_bf16(a1, bf, acc[1][t], 0, 0, 0);
      }
    }
  } else {
    const int swz0 = (cr & 7) << 4;          // same key for rows cr and 16+cr
    #pragma unroll
    for (int ks = 0; ks < 10; ++ks) {
      const int b0 = (cr * 640        + ks * 64 + kh * 16) ^ swz0;
      const int b1 = ((16 + cr) * 640 + ks * 64 + kh * 16) ^ swz0;
      const bf16x8 a0 = *(const bf16x8*)(smem + b0);
      const bf16x8 a1 = *(const bf16x8*)(smem + b1);
      #pragma unroll
      for (int t = 0; t < 5; ++t) {
        const bf16x8 bf = *(const bf16x8*)(wp[t] + ks * 32);
        acc[0][t] = __builtin_amdgcn_mfma_f32_16x16x32_bf16(a0, bf, acc[0][t], 0, 0, 0);
        acc[1][t] = __builtin_amdgcn_mfma_f32_16x16x32_bf16(a1, bf, acc[1][t], 0, 0, 0);
      }
    }
    __syncthreads();                         // seg reads done; LDS reused for cout
  }

  // ---- phase 3: bias + relu + /R -> fp32 LDS tile [32][CSTR] ----
  float* __restrict__ cout = (float*)smem;
  const float inv_r = 1.0f / (float)R;
  #pragma unroll
  for (int t = 0; t < 5; ++t) {
    const int col = (wv * 5 + t) * 16 + cr;
    if (col < D) {
      const float bv = bias[N * D + col];
      #pragma unroll
      for (int mt = 0; mt < 2; ++mt)
        #pragma unroll
        for (int j = 0; j < 4; ++j) {
          const int row = mt * 16 + kh * 4 + j;
          cout[row * CSTR + col] = fmaxf(acc[mt][t][j] + bv, 0.f) * inv_r;
        }
    }
  }
  __syncthreads();

  // ---- phase 4: coalesced float4 stores, repeats included ----
  constexpr int TOTAL = 32 * R * 75;
  for (int i = tid; i < TOTAL; i += 256) {
    const int rowrep = i / 75;
    const int chunk  = i - rowrep * 75;
    const int ml     = rowrep / R;
    const int q      = rowrep - ml * R;
    const int m      = m0 + ml;
    const int bb     = m / G;
    const int grp    = m - bb * G;
    const f32x4 v = *(const f32x4*)(cout + ml * CSTR + chunk * 4);
    float* __restrict__ op =
        out + ((size_t)((N * 64 + bb) * LSEQ) + grp * R + q) * D + chunk * 4;
    *(f32x4*)op = v;
  }
}

__global__ __launch_bounds__(256, 4)
void ce_mfma6(const float* __restrict__ x, const short* __restrict__ Wb,
              const float* __restrict__ bias, float* __restrict__ out) {
  __shared__ __align__(16) char smem[SMEM_BYTES];
  // super-chunk interleave: 16 chunks x 189 blocks; all scales share the
  // same 4-batch-row x-window within a chunk; heavy-r first.
  const int bid = blockIdx.x;
  const int sc  = bid / 189;
  const int o   = bid - sc * 189;
  if (o < 4)        ce_body<4, 25, 32 >(sc * 4   + o,        smem, x, Wb, bias, out);
  else if (o < 14)  ce_body<3, 10, 80 >(sc * 10  + (o - 4),  smem, x, Wb, bias, out);
  else if (o < 39)  ce_body<2, 4, 200 >(sc * 25  + (o - 14), smem, x, Wb, bias, out);
  else if (o < 89)  ce_body<1, 2, 400 >(sc * 50  + (o - 39), smem, x, Wb, bias, out);
  else              ce_body<0, 1, 800 >(sc * 100 + (o - 89), smem, x, Wb, bias, out);
}

extern "C" void kernel_launch(void* const* d_in, const int* in_sizes, int n_in,
                              void* d_out, int out_size, void* d_ws, size_t ws_size,
                              hipStream_t stream) {
  const float* x    = (const float*)d_in[0];  // [64, 800, 300]
  const float* W    = (const float*)d_in[1];  // [5, 300, 300]
  const float* bias = (const float*)d_in[2];  // [5, 300]
  float* out        = (float*)d_out;          // [5, 64, 800, 300]
  short* Wb         = (short*)d_ws;           // [5][320][320] bf16, ~1 MB

  convert_w<<<(5 * NP * KP + 255) / 256, 256, 0, stream>>>(W, Wb);
  ce_mfma6<<<3024, 256, 0, stream>>>(x, Wb, bias, out);
}